// Round 1
// baseline (1011.482 us; speedup 1.0000x reference)
//
#include <hip/hip_runtime.h>
#include <math.h>

// Problem constants (fixed by the reference):
//   B = 16384, D = 4096, D+3 = 4099 features, H = 128 hidden, E = 64 experts, K = 8
#define DGL 4096
#define HGL 128
#define EGL 64
#define BM  32     // rows per block
#define BKC 32     // k-chunk

// LDS layout (bytes), unioned:
//   [0,      4608)  As  [32][36]   (phase A)      \ union with
//   [4608,  20992)  Bs  [32][128]  (phase A)      /  w2s [128][64] at [0,32768) (phase C)
//   [32768, 51200)  hs  [128][36]  (phase B->C)   union with ls[32][65] + wt[32][65] (phase D/E)
#define SMEM_BYTES 51200
#define OFF_BS     4608
#define OFF_W2S    0
#define OFF_HS     32768
#define OFF_LS     32768
#define OFF_WT     (32768 + 8320)

__global__ __launch_bounds__(256, 2) void router_kernel(
    const float* __restrict__ r_pooled,   // [B][4096]
    const float* __restrict__ step_frac,  // [1]
    const float* __restrict__ hidden_norm,// [B]
    const float* __restrict__ confidence, // [B]
    const float* __restrict__ W1,         // [4099][128]
    const float* __restrict__ b1,         // [128]
    const float* __restrict__ W2,         // [128][64]
    const float* __restrict__ b2,         // [64]
    float* __restrict__ out_weights,      // [B][64]
    float* __restrict__ out_logits)       // [B][64]
{
    __shared__ __align__(16) char smem[SMEM_BYTES];
    float* As  = reinterpret_cast<float*>(smem);            // [32][36] transposed A: As[k][m]
    float* Bs  = reinterpret_cast<float*>(smem + OFF_BS);   // [32][128] Bs[k][c]
    float* w2s = reinterpret_cast<float*>(smem + OFF_W2S);  // [128][64]
    float* hs  = reinterpret_cast<float*>(smem + OFF_HS);   // [128][36] hs[c][m]
    float* ls  = reinterpret_cast<float*>(smem + OFF_LS);   // [32][65] logits tile
    float* wt  = reinterpret_cast<float*>(smem + OFF_WT);   // [32][65] weights tile

    const int t    = threadIdx.x;
    const int row0 = blockIdx.x * BM;

    // compute-thread mapping: 16 m-groups (TM=2) x 16 n-groups (TN=4+4 split at +64)
    const int mg = t >> 4;       // 0..15
    const int ng = t & 15;       // 0..15
    const int m0 = mg * 2;       // rows m0, m0+1
    const int cn = ng * 4;       // cols cn..cn+3 and cn+64..cn+67

    // A-staging mapping: 8 k-groups x 32 rows
    const int a_kg = t & 7;      // *4 = k offset
    const int a_m  = t >> 3;     // 0..31
    const size_t a_base = (size_t)(row0 + a_m) * DGL + a_kg * 4;
    // B-staging mapping: 32 col-groups x 8 k
    const int b_c = (t & 31) * 4;
    const int b_k = t >> 5;      // 0..7

    float acc[2][8];
#pragma unroll
    for (int i = 0; i < 2; ++i)
#pragma unroll
        for (int j = 0; j < 8; ++j) acc[i][j] = 0.0f;

    // ---------------- Phase A: GEMM1 over K=4096 ----------------
    for (int kc = 0; kc < DGL; kc += BKC) {
        // global prefetch into regs
        const float4 aload = *reinterpret_cast<const float4*>(&r_pooled[a_base + kc]);
        float4 bload[4];
#pragma unroll
        for (int p = 0; p < 4; ++p)
            bload[p] = *reinterpret_cast<const float4*>(
                &W1[(size_t)(kc + b_k + p * 8) * HGL + b_c]);

        __syncthreads();  // previous chunk's compute done
        {
            const float* af = reinterpret_cast<const float*>(&aload);
#pragma unroll
            for (int j = 0; j < 4; ++j)
                As[(a_kg * 4 + j) * 36 + a_m] = af[j];     // transpose into LDS
#pragma unroll
            for (int p = 0; p < 4; ++p)
                *reinterpret_cast<float4*>(&Bs[(b_k + p * 8) * HGL + b_c]) = bload[p];
        }
        __syncthreads();

#pragma unroll
        for (int k = 0; k < BKC; ++k) {
            const float2 a  = *reinterpret_cast<const float2*>(&As[k * 36 + m0]);
            const float4 bl = *reinterpret_cast<const float4*>(&Bs[k * HGL + cn]);
            const float4 bh = *reinterpret_cast<const float4*>(&Bs[k * HGL + cn + 64]);
            float ar[2]; ar[0] = a.x; ar[1] = a.y;
            float br[8];
            br[0] = bl.x; br[1] = bl.y; br[2] = bl.z; br[3] = bl.w;
            br[4] = bh.x; br[5] = bh.y; br[6] = bh.z; br[7] = bh.w;
#pragma unroll
            for (int i = 0; i < 2; ++i)
#pragma unroll
                for (int j = 0; j < 8; ++j)
                    acc[i][j] = fmaf(ar[i], br[j], acc[i][j]);
        }
    }

    // ---------------- Phase B: 3 concat features + bias + silu -> hs ----------------
    {
        const float sf = step_frac[0];
        float wsf[8], whn[8], wcf[8], bb[8];
#pragma unroll
        for (int j = 0; j < 8; ++j) {
            const int cj = cn + (j & 3) + ((j >> 2) << 6);
            wsf[j] = W1[(size_t)4096 * HGL + cj];
            whn[j] = W1[(size_t)4097 * HGL + cj];
            wcf[j] = W1[(size_t)4098 * HGL + cj];
            bb[j]  = b1[cj];
        }
#pragma unroll
        for (int i = 0; i < 2; ++i) {
            const int row = row0 + m0 + i;
            const float hn = hidden_norm[row];
            const float cf = confidence[row];
#pragma unroll
            for (int j = 0; j < 8; ++j) {
                const int cj = cn + (j & 3) + ((j >> 2) << 6);
                const float x = acc[i][j] + sf * wsf[j] + hn * whn[j] + cf * wcf[j] + bb[j];
                const float hv = x / (1.0f + expf(-x));   // exact silu
                hs[cj * 36 + m0 + i] = hv;                // transposed: hs[c][m]
            }
        }
    }

    // ---------------- Phase C: GEMM2 (K=128, E=64) ----------------
    __syncthreads();  // hs written; As/Bs dead -> stage W2 over them
    {
        const int kw = t >> 4;   // 0..15
#pragma unroll
        for (int p = 0; p < 8; ++p) {
            const int k = kw + p * 16;
            *reinterpret_cast<float4*>(&w2s[k * EGL + cn]) =
                *reinterpret_cast<const float4*>(&W2[k * EGL + cn]);
        }
    }
    __syncthreads();

    float acc2[2][4];
#pragma unroll
    for (int i = 0; i < 2; ++i)
#pragma unroll
        for (int j = 0; j < 4; ++j) acc2[i][j] = 0.0f;

#pragma unroll 8
    for (int k = 0; k < HGL; ++k) {
        const float2 a = *reinterpret_cast<const float2*>(&hs[k * 36 + m0]);
        const float4 w = *reinterpret_cast<const float4*>(&w2s[k * EGL + cn]);
        acc2[0][0] = fmaf(a.x, w.x, acc2[0][0]);
        acc2[0][1] = fmaf(a.x, w.y, acc2[0][1]);
        acc2[0][2] = fmaf(a.x, w.z, acc2[0][2]);
        acc2[0][3] = fmaf(a.x, w.w, acc2[0][3]);
        acc2[1][0] = fmaf(a.y, w.x, acc2[1][0]);
        acc2[1][1] = fmaf(a.y, w.y, acc2[1][1]);
        acc2[1][2] = fmaf(a.y, w.z, acc2[1][2]);
        acc2[1][3] = fmaf(a.y, w.w, acc2[1][3]);
    }
#pragma unroll
    for (int j = 0; j < 4; ++j) {
        const float bv = b2[cn + j];
        acc2[0][j] += bv;
        acc2[1][j] += bv;
    }

    // ---------------- Phase D: emit logits, stage tile for topk ----------------
    __syncthreads();  // hs reads done; ls/wt overlay the hs region
#pragma unroll
    for (int i = 0; i < 2; ++i) {
        const int row = row0 + m0 + i;
        float4 lv;
        lv.x = acc2[i][0]; lv.y = acc2[i][1]; lv.z = acc2[i][2]; lv.w = acc2[i][3];
        *reinterpret_cast<float4*>(&out_logits[(size_t)row * EGL + cn]) = lv;
#pragma unroll
        for (int j = 0; j < 4; ++j)
            ls[(m0 + i) * 65 + cn + j] = acc2[i][j];
    }
    for (int idx = t; idx < 32 * 65; idx += 256) wt[idx] = 0.0f;
    __syncthreads();

    // ---------------- Phase E: top-8 + softmax + scatter ----------------
    if (t < BM) {
        float vals[8];
        int   idxs[8];
#pragma unroll
        for (int i = 0; i < 8; ++i) { vals[i] = -INFINITY; idxs[i] = 0; }
        for (int e = 0; e < EGL; ++e) {
            const float v = ls[t * 65 + e];
            if (v > vals[7]) {
                int p = 7;
                // strict '>' keeps earlier (lower) index ahead on ties, matching jax top_k
                while (p > 0 && v > vals[p - 1]) {
                    vals[p] = vals[p - 1];
                    idxs[p] = idxs[p - 1];
                    --p;
                }
                vals[p] = v;
                idxs[p] = e;
            }
        }
        const float mx = vals[0];
        float w[8], s = 0.0f;
#pragma unroll
        for (int i = 0; i < 8; ++i) { w[i] = expf(vals[i] - mx); s += w[i]; }
        const float inv = 1.0f / s;
#pragma unroll
        for (int i = 0; i < 8; ++i)
            wt[t * 65 + idxs[i]] = w[i] * inv;
    }
    __syncthreads();

    // coalesced weights write
    for (int idx = t; idx < BM * EGL; idx += 256) {
        const int m = idx >> 6;
        const int e = idx & 63;
        out_weights[(size_t)(row0 + m) * EGL + e] = wt[m * 65 + e];
    }
}

extern "C" void kernel_launch(void* const* d_in, const int* in_sizes, int n_in,
                              void* d_out, int out_size, void* d_ws, size_t ws_size,
                              hipStream_t stream) {
    const float* r_pooled    = (const float*)d_in[0];
    const float* step_frac   = (const float*)d_in[1];
    const float* hidden_norm = (const float*)d_in[2];
    const float* confidence  = (const float*)d_in[3];
    const float* W1          = (const float*)d_in[4];
    const float* b1          = (const float*)d_in[5];
    const float* W2          = (const float*)d_in[6];
    const float* b2          = (const float*)d_in[7];

    const int B = in_sizes[2];               // hidden_norm length
    float* out_w = (float*)d_out;            // weights first
    float* out_l = out_w + (size_t)B * EGL;  // then logits

    dim3 grid(B / BM), block(256);
    hipLaunchKernelGGL(router_kernel, grid, block, 0, stream,
                       r_pooled, step_frac, hidden_norm, confidence,
                       W1, b1, W2, b2, out_w, out_l);
}

// Round 2
// 649.464 us; speedup vs baseline: 1.5574x; 1.5574x over previous
//
#include <hip/hip_runtime.h>
#include <math.h>

// B=16384, D=4096 (+3 tail features), H=128, E=64, K=8
#define DGL 4096
#define HGL 128
#define EGL 64
#define BM  32
#define NKC 128            // 4096 / 32
#define DELTA 5e-4f        // gap threshold for fp32 recompute (err sigma ~1.5e-5)

typedef short  short8 __attribute__((ext_vector_type(8)));
typedef float  f32x4  __attribute__((ext_vector_type(4)));

__device__ inline unsigned short bf16_rne(float x) {
    unsigned u = __float_as_uint(x);
    u += 0x7FFFu + ((u >> 16) & 1u);
    return (unsigned short)(u >> 16);
}

// truncation-hi + RNE-lo split: hi+lo represents x to ~2^-17 rel
__device__ inline void split2(float x, short& hi, short& lo) {
    unsigned u = __float_as_uint(x);
    hi = (short)(u >> 16);
    float hif = __uint_as_float(u & 0xFFFF0000u);
    lo = (short)bf16_rne(x - hif);
}

__device__ inline void async_lds16(const void* g, void* lds) {
    __builtin_amdgcn_global_load_lds(
        (__attribute__((address_space(1))) void*)g,
        (__attribute__((address_space(3))) void*)lds, 16, 0, 0);
}

// ---------------- kernel 1: pack W1[0:4096] into bf16 hi/lo MFMA B-fragments ----------------
// layout (ushort): ws[kc*8192 + (nt*2+h)*512 + lane*8 + j]
//   fragment: lane l holds B[k = kc*32 + (l>>4)*8 + j][n = nt*16 + (l&15)]
__global__ void pack_w1(const float* __restrict__ W1, unsigned short* __restrict__ wsB) {
    const int b   = blockIdx.x;       // 1024 = 128 kc * 8 nt
    const int kci = b >> 3, nt = b & 7;
    const int l   = threadIdx.x;      // 64
    const int quad = l >> 4, l15 = l & 15;
    short hi[8], lo[8];
#pragma unroll
    for (int j = 0; j < 8; ++j) {
        const int k = kci * 32 + quad * 8 + j;
        const float x = W1[(size_t)k * HGL + nt * 16 + l15];
        split2(x, hi[j], lo[j]);
    }
    short8 vh, vl;
#pragma unroll
    for (int j = 0; j < 8; ++j) { vh[j] = hi[j]; vl[j] = lo[j]; }
    *(short8*)(wsB + (size_t)kci * 8192 + ((nt * 2 + 0) * 64 + l) * 8) = vh;
    *(short8*)(wsB + (size_t)kci * 8192 + ((nt * 2 + 1) * 64 + l) * 8) = vl;
}

// ---------------- kernel 2: main fused router ----------------
// LDS: As dbuf 2x4KB @0 | w2s 32KB @8192 | hs 128x36 f32 @40960 ; ls/wt overlay @0/@8320 after GEMM2
#define SMEM_BYTES (8192 + 32768 + 18432)

__global__ __launch_bounds__(256, 2) void router_main(
    const float* __restrict__ r_pooled, const float* __restrict__ step_frac,
    const float* __restrict__ hn, const float* __restrict__ cf,
    const float* __restrict__ W1, const float* __restrict__ b1,
    const float* __restrict__ W2, const float* __restrict__ b2,
    const unsigned short* __restrict__ wsB, int* __restrict__ flags,
    float* __restrict__ out_w, float* __restrict__ out_l)
{
    __shared__ __align__(16) char smem[SMEM_BYTES];
    char*  AsBase = smem;                         // 2 x 4096 B (32 rows x 32 fp32, swizzled)
    float* w2s = (float*)(smem + 8192);           // [128][64] f32
    float* hs  = (float*)(smem + 8192 + 32768);   // [128][36] f32
    float* ls  = (float*)smem;                    // [32][65] (overlay, post-GEMM2)
    float* wt  = (float*)(smem + 8320);           // [32][65]

    const int t = threadIdx.x;
    const int w = t >> 6, l = t & 63;
    const int quad = l >> 4, l15 = l & 15;
    const int row0 = blockIdx.x * BM;
    const int mt = w >> 1, nh = w & 1;            // wave role: m-tile (0/1), n-half (0/1)

    // w2s staging (once, async; drained by first barrier)
    for (int q = 0; q < 8; ++q) {
        const int sidx = (w * 8 + q) * 64 + l;    // 0..2047 -> 16B each
        async_lds16(W2 + sidx * 4, (char*)w2s + (w * 8 + q) * 1024);
    }

    // A staging mapping (per lane): linear idx t -> row t>>3, 16B-block t&7, XOR-swizzled source
    const int arow = t >> 3, ablk = t & 7;
    const float* aSrc = r_pooled + (size_t)(row0 + arow) * DGL + ((ablk ^ (arow & 7)) << 2);

    auto issueA = [&](int kci, int buf) {
        async_lds16(aSrc + kci * 32, AsBase + buf * 4096 + w * 1024);
    };
    auto loadB = [&](int kci, short8* bh, short8* bl) {
        const unsigned short* base = wsB + (size_t)kci * 8192;
#pragma unroll
        for (int i = 0; i < 4; ++i) {
            const int nt = nh * 4 + i;
            bh[i] = *(const short8*)(base + ((nt * 2 + 0) * 64 + l) * 8);
            bl[i] = *(const short8*)(base + ((nt * 2 + 1) * 64 + l) * 8);
        }
    };

    f32x4 acc[4];
#pragma unroll
    for (int i = 0; i < 4; ++i) acc[i] = (f32x4){0.f, 0.f, 0.f, 0.f};

    const int rl = mt * 16 + l15;                 // local row this lane reads for A-frags
    const int s  = l15 & 7;                       // swizzle key

    auto compute = [&](int buf, const short8* bh, const short8* bl) {
        const char* Asb = AsBase + buf * 4096;
        const int plo = ((quad << 1)) ^ s;
        const int phi = ((quad << 1) | 1) ^ s;
        f32x4 va = *(const f32x4*)(Asb + rl * 128 + plo * 16);   // k = quad*8 + 0..3
        f32x4 vb = *(const f32x4*)(Asb + rl * 128 + phi * 16);   // k = quad*8 + 4..7
        float fa[8];
#pragma unroll
        for (int j = 0; j < 4; ++j) { fa[j] = va[j]; fa[j + 4] = vb[j]; }
        short8 ahi, alo;
#pragma unroll
        for (int j = 0; j < 8; ++j) { short h, lo2; split2(fa[j], h, lo2); ahi[j] = h; alo[j] = lo2; }
#pragma unroll
        for (int i = 0; i < 4; ++i) {
            acc[i] = __builtin_amdgcn_mfma_f32_16x16x32_bf16(ahi, bh[i], acc[i], 0, 0, 0);
            acc[i] = __builtin_amdgcn_mfma_f32_16x16x32_bf16(ahi, bl[i], acc[i], 0, 0, 0);
            acc[i] = __builtin_amdgcn_mfma_f32_16x16x32_bf16(alo, bh[i], acc[i], 0, 0, 0);
        }
    };

    short8 bh0[4], bl0[4], bh1[4], bl1[4];
    loadB(0, bh0, bl0);
    issueA(0, 0);

    for (int kci = 0; kci < NKC; kci += 2) {
        __syncthreads();                               // As[0] ready
        if (kci + 1 < NKC) { issueA(kci + 1, 1); loadB(kci + 1, bh1, bl1); }
        compute(0, bh0, bl0);
        __syncthreads();                               // As[1] ready
        if (kci + 2 < NKC) { issueA(kci + 2, 0); loadB(kci + 2, bh0, bl0); }
        compute(1, bh1, bl1);
    }

    // -------- epilogue: tail features + bias + silu -> hs[c][m] --------
    {
        const float sf = step_frac[0];
        const int rbase = row0 + mt * 16 + quad * 4;
        float hnv[4], cfv[4];
#pragma unroll
        for (int r = 0; r < 4; ++r) { hnv[r] = hn[rbase + r]; cfv[r] = cf[rbase + r]; }
#pragma unroll
        for (int i = 0; i < 4; ++i) {
            const int c = nh * 64 + i * 16 + l15;
            const float w96 = W1[(size_t)4096 * HGL + c];
            const float w97 = W1[(size_t)4097 * HGL + c];
            const float w98 = W1[(size_t)4098 * HGL + c];
            const float bb  = b1[c];
#pragma unroll
            for (int r = 0; r < 4; ++r) {
                const float x = acc[i][r] + sf * w96 + hnv[r] * w97 + cfv[r] * w98 + bb;
                hs[c * 36 + (mt * 16 + quad * 4 + r)] = x / (1.0f + expf(-x));
            }
        }
    }
    __syncthreads();   // hs complete; w2s long since loaded

    // -------- GEMM2 (fp32, K=128, E=64) --------
    const int mg = t >> 4, ng = t & 15;
    const int m0 = mg * 2, cn0 = ng * 4;
    float acc2[2][4];
#pragma unroll
    for (int i = 0; i < 2; ++i)
#pragma unroll
        for (int j = 0; j < 4; ++j) acc2[i][j] = 0.0f;

#pragma unroll 8
    for (int k = 0; k < HGL; ++k) {
        const float2 a = *(const float2*)&hs[k * 36 + m0];
        const float4 wv = *(const float4*)&w2s[k * 64 + cn0];
        acc2[0][0] = fmaf(a.x, wv.x, acc2[0][0]);
        acc2[0][1] = fmaf(a.x, wv.y, acc2[0][1]);
        acc2[0][2] = fmaf(a.x, wv.z, acc2[0][2]);
        acc2[0][3] = fmaf(a.x, wv.w, acc2[0][3]);
        acc2[1][0] = fmaf(a.y, wv.x, acc2[1][0]);
        acc2[1][1] = fmaf(a.y, wv.y, acc2[1][1]);
        acc2[1][2] = fmaf(a.y, wv.z, acc2[1][2]);
        acc2[1][3] = fmaf(a.y, wv.w, acc2[1][3]);
    }
#pragma unroll
    for (int j = 0; j < 4; ++j) {
        const float bv = b2[cn0 + j];
        acc2[0][j] += bv; acc2[1][j] += bv;
    }
    __syncthreads();   // everyone done reading w2s/hs before ls/wt overlay writes

    // -------- emit logits + stage ls, zero wt --------
#pragma unroll
    for (int i = 0; i < 2; ++i) {
        const int row = row0 + m0 + i;
        float4 lv; lv.x = acc2[i][0]; lv.y = acc2[i][1]; lv.z = acc2[i][2]; lv.w = acc2[i][3];
        *(float4*)&out_l[(size_t)row * EGL + cn0] = lv;
#pragma unroll
        for (int j = 0; j < 4; ++j) ls[(m0 + i) * 65 + cn0 + j] = acc2[i][j];
    }
    for (int idx = t; idx < 32 * 65; idx += 256) wt[idx] = 0.0f;
    __syncthreads();

    // -------- top-8 (+9th for gap), softmax, scatter, flag --------
    if (t < BM) {
        float vals[9]; int idxs[9];
#pragma unroll
        for (int i = 0; i < 9; ++i) { vals[i] = -INFINITY; idxs[i] = 0; }
        for (int e = 0; e < EGL; ++e) {
            const float v = ls[t * 65 + e];
            if (v > vals[8]) {
                int p = 8;
                while (p > 0 && v > vals[p - 1]) { vals[p] = vals[p - 1]; idxs[p] = idxs[p - 1]; --p; }
                vals[p] = v; idxs[p] = e;
            }
        }
        flags[row0 + t] = (vals[7] - vals[8] < DELTA) ? 1 : 0;
        const float mx = vals[0];
        float wgt[8], ssum = 0.0f;
#pragma unroll
        for (int i = 0; i < 8; ++i) { wgt[i] = expf(vals[i] - mx); ssum += wgt[i]; }
        const float inv = 1.0f / ssum;
#pragma unroll
        for (int i = 0; i < 8; ++i) wt[t * 65 + idxs[i]] = wgt[i] * inv;
    }
    __syncthreads();

    for (int idx = t; idx < BM * EGL; idx += 256) {
        const int m = idx >> 6, e = idx & 63;
        out_w[(size_t)(row0 + m) * EGL + e] = wt[m * 65 + e];
    }
}

// ---------------- kernel 3: fp32 recompute of flagged (near-tie) rows ----------------
__global__ __launch_bounds__(256, 2) void refine_rows(
    const float* __restrict__ r_pooled, const float* __restrict__ step_frac,
    const float* __restrict__ hn, const float* __restrict__ cf,
    const float* __restrict__ W1, const float* __restrict__ b1,
    const float* __restrict__ W2, const float* __restrict__ b2,
    const int* __restrict__ flags, float* __restrict__ out_w, float* __restrict__ out_l)
{
    __shared__ int rlist[32];
    __shared__ int rcount;
    __shared__ __align__(16) float als[4][1024];
    __shared__ float hred[4][128];
    __shared__ float lbuf[4][64];
    __shared__ float wbuf[4][64];

    const int t = threadIdx.x;
    const int row0 = blockIdx.x * 32;
    if (t == 0) rcount = 0;
    __syncthreads();
    if (t < 32 && flags[row0 + t]) { int p = atomicAdd(&rcount, 1); rlist[p] = row0 + t; }
    __syncthreads();
    const int n = rcount;
    if (n == 0) return;

    const int c = t & 127, half = t >> 7;
    for (int g = 0; g < n; g += 4) {
        const int R = min(4, n - g);
        float pr[4] = {0.f, 0.f, 0.f, 0.f};
        for (int kc2 = 0; kc2 < DGL; kc2 += 1024) {
            __syncthreads();
            for (int i = 0; i < R; ++i)
                *(float4*)&als[i][t * 4] =
                    *(const float4*)&r_pooled[(size_t)rlist[g + i] * DGL + kc2 + t * 4];
            __syncthreads();
            const float* wp = W1 + (size_t)(kc2 + half * 512) * HGL + c;
            const float* ap = &als[0][half * 512];
#pragma unroll 4
            for (int j = 0; j < 512; ++j) {
                const float wv = wp[(size_t)j * HGL];
#pragma unroll
                for (int i = 0; i < 4; ++i) pr[i] += als[i][half * 512 + j] * wv;
            }
            (void)ap;
        }
        __syncthreads();
        if (half == 0) { for (int i = 0; i < 4; ++i) hred[i][c] = pr[i]; }
        __syncthreads();
        if (half == 1) { for (int i = 0; i < 4; ++i) hred[i][c] += pr[i]; }
        __syncthreads();
        if (t < 128) {
            const float sf = step_frac[0];
            const float w96 = W1[(size_t)4096 * HGL + t];
            const float w97 = W1[(size_t)4097 * HGL + t];
            const float w98 = W1[(size_t)4098 * HGL + t];
            const float bb  = b1[t];
            for (int i = 0; i < R; ++i) {
                const int r = rlist[g + i];
                const float x = hred[i][t] + sf * w96 + hn[r] * w97 + cf[r] * w98 + bb;
                hred[i][t] = x / (1.0f + expf(-x));
            }
        }
        __syncthreads();
        if (t < 64) {
            for (int i = 0; i < R; ++i) {
                float acc = b2[t];
                for (int k = 0; k < HGL; ++k) acc += hred[i][k] * W2[k * EGL + t];
                lbuf[i][t] = acc; wbuf[i][t] = 0.0f;
                out_l[(size_t)rlist[g + i] * EGL + t] = acc;
            }
        }
        __syncthreads();
        if (t < R) {
            float vals[8]; int idxs[8];
#pragma unroll
            for (int i = 0; i < 8; ++i) { vals[i] = -INFINITY; idxs[i] = 0; }
            for (int e = 0; e < EGL; ++e) {
                const float v = lbuf[t][e];
                if (v > vals[7]) {
                    int p = 7;
                    while (p > 0 && v > vals[p - 1]) { vals[p] = vals[p - 1]; idxs[p] = idxs[p - 1]; --p; }
                    vals[p] = v; idxs[p] = e;
                }
            }
            const float mx = vals[0];
            float wgt[8], ssum = 0.0f;
#pragma unroll
            for (int i = 0; i < 8; ++i) { wgt[i] = expf(vals[i] - mx); ssum += wgt[i]; }
            const float inv = 1.0f / ssum;
#pragma unroll
            for (int i = 0; i < 8; ++i) wbuf[t][idxs[i]] = wgt[i] * inv;
        }
        __syncthreads();
        if (t < 64) {
            for (int i = 0; i < R; ++i) out_w[(size_t)rlist[g + i] * EGL + t] = wbuf[i][t];
        }
        __syncthreads();
    }
}

extern "C" void kernel_launch(void* const* d_in, const int* in_sizes, int n_in,
                              void* d_out, int out_size, void* d_ws, size_t ws_size,
                              hipStream_t stream) {
    const float* r_pooled    = (const float*)d_in[0];
    const float* step_frac   = (const float*)d_in[1];
    const float* hidden_norm = (const float*)d_in[2];
    const float* confidence  = (const float*)d_in[3];
    const float* W1          = (const float*)d_in[4];
    const float* b1          = (const float*)d_in[5];
    const float* W2          = (const float*)d_in[6];
    const float* b2          = (const float*)d_in[7];

    const int B = in_sizes[2];
    float* out_w = (float*)d_out;
    float* out_l = out_w + (size_t)B * EGL;

    unsigned short* wsB = (unsigned short*)d_ws;            // 2 MB packed W1 frags
    int* flags = (int*)((char*)d_ws + (2u << 20));          // 64 KB flags

    hipLaunchKernelGGL(pack_w1, dim3(1024), dim3(64), 0, stream, W1, wsB);
    hipLaunchKernelGGL(router_main, dim3(B / BM), dim3(256), 0, stream,
                       r_pooled, step_frac, hidden_norm, confidence,
                       W1, b1, W2, b2, wsB, flags, out_w, out_l);
    hipLaunchKernelGGL(refine_rows, dim3(B / 32), dim3(256), 0, stream,
                       r_pooled, step_frac, hidden_norm, confidence,
                       W1, b1, W2, b2, flags, out_w, out_l);
}

// Round 3
// 619.784 us; speedup vs baseline: 1.6320x; 1.0479x over previous
//
#include <hip/hip_runtime.h>
#include <math.h>

// B=16384, D=4096 (+3 tail features), H=128, E=64, K=8
#define DGL 4096
#define HGL 128
#define EGL 64
#define DELTA 5e-4f    // top8/9 gap threshold for fp32 recompute (split err sigma ~1.5e-5)

typedef short  short8 __attribute__((ext_vector_type(8)));
typedef float  f32x4  __attribute__((ext_vector_type(4)));

__device__ inline unsigned short bf16_rne(float x) {
    unsigned u = __float_as_uint(x);
    u += 0x7FFFu + ((u >> 16) & 1u);
    return (unsigned short)(u >> 16);
}
// truncation-hi + RNE-lo split: hi+lo represents x to ~2^-17 rel
__device__ inline void split2(float x, short& hi, short& lo) {
    unsigned u = __float_as_uint(x);
    hi = (short)(u >> 16);
    float hif = __uint_as_float(u & 0xFFFF0000u);
    lo = (short)bf16_rne(x - hif);
}
__device__ inline void split8(const float* f, short8& hi, short8& lo) {
#pragma unroll
    for (int j = 0; j < 8; ++j) { short h, l2; split2(f[j], h, l2); hi[j] = h; lo[j] = l2; }
}

// ---- pack W1[0:4096] into bf16 hi/lo MFMA B-fragments (verified layout, round 2) ----
// wsB1[kci*8192 + ((nt*2+h)*64 + lane)*8 + j]; lane l holds B[k=kci*32+(l>>4)*8+j][n=nt*16+(l&15)]
__global__ void pack_w1(const float* __restrict__ W1, unsigned short* __restrict__ wsB1) {
    const int b = blockIdx.x;              // 1024 = 128 kci * 8 nt
    const int kci = b >> 3, nt = b & 7;
    const int l = threadIdx.x, quad = l >> 4, l15 = l & 15;
    short8 vh, vl;
#pragma unroll
    for (int j = 0; j < 8; ++j) {
        const int k = kci * 32 + quad * 8 + j;
        short h, lo; split2(W1[(size_t)k * HGL + nt * 16 + l15], h, lo);
        vh[j] = h; vl[j] = lo;
    }
    *(short8*)(wsB1 + (size_t)kci * 8192 + ((nt * 2 + 0) * 64 + l) * 8) = vh;
    *(short8*)(wsB1 + (size_t)kci * 8192 + ((nt * 2 + 1) * 64 + l) * 8) = vl;
}

// ---- pack W2 (128x64) frags; also zero the refine-list counter ----
// wsB2[((kc2*4+nt)*2+h)*512 + lane*8 + j]; k=kc2*32+(l>>4)*8+j, n=nt*16+(l&15)
__global__ void pack_w2(const float* __restrict__ W2, unsigned short* __restrict__ wsB2,
                        int* __restrict__ gcount) {
    if (blockIdx.x == 0 && threadIdx.x == 0) *gcount = 0;
    const int b = blockIdx.x;              // 16 = 4 kc2 * 4 nt
    const int kc2 = b >> 2, nt = b & 3;
    const int l = threadIdx.x, quad = l >> 4, l15 = l & 15;
    short8 vh, vl;
#pragma unroll
    for (int j = 0; j < 8; ++j) {
        const int k = kc2 * 32 + quad * 8 + j;
        short h, lo; split2(W2[k * EGL + nt * 16 + l15], h, lo);
        vh[j] = h; vl[j] = lo;
    }
    *(short8*)(wsB2 + ((kc2 * 4 + nt) * 2 + 0) * 512 + l * 8) = vh;
    *(short8*)(wsB2 + ((kc2 * 4 + nt) * 2 + 1) * 512 + l * 8) = vl;
}

// ---- main: 1 wave per block, 32 rows/wave, NO LDS / NO barriers in the K-loop ----
__global__ __launch_bounds__(64, 1) void router_main(
    const float* __restrict__ r_pooled, const float* __restrict__ step_frac,
    const float* __restrict__ hn, const float* __restrict__ cf,
    const float* __restrict__ W1, const float* __restrict__ b1,
    const float* __restrict__ b2v,
    const unsigned short* __restrict__ wsB1, const unsigned short* __restrict__ wsB2,
    int* __restrict__ gcount, int* __restrict__ glist,
    float* __restrict__ out_w, float* __restrict__ out_l)
{
    __shared__ float hs[32 * 132];   // h transposed staging for GEMM2 A-frags
    __shared__ float ls[32 * 65];    // logits tile for topk
    __shared__ float wt[32 * 65];    // weights tile

    const int l = threadIdx.x;
    const int quad = l >> 4, l15 = l & 15;
    const int row0 = blockIdx.x * 32;

    // A-frag sources: lane holds A[row=l15(+16m)][k=quad*8+j]
    const float* aB0 = r_pooled + (size_t)(row0 + l15) * DGL + quad * 8;
    const float* aB1 = aB0 + (size_t)16 * DGL;

    f32x4 acc[2][8];
#pragma unroll
    for (int m = 0; m < 2; ++m)
#pragma unroll
        for (int nt = 0; nt < 8; ++nt) acc[m][nt] = (f32x4){0.f, 0.f, 0.f, 0.f};

    float4 a0[4];
    a0[0] = *(const float4*)(aB0);
    a0[1] = *(const float4*)(aB0 + 4);
    a0[2] = *(const float4*)(aB1);
    a0[3] = *(const float4*)(aB1 + 4);

    for (int kci = 0; kci < 128; ++kci) {
        // prefetch next A chunk (HBM) one iteration ahead
        const int kn = (kci + 1 < 128) ? (kci + 1) : 127;
        float4 a1[4];
        a1[0] = *(const float4*)(aB0 + kn * 32);
        a1[1] = *(const float4*)(aB0 + kn * 32 + 4);
        a1[2] = *(const float4*)(aB1 + kn * 32);
        a1[3] = *(const float4*)(aB1 + kn * 32 + 4);

        // B frags for this kci from L2-resident workspace
        const unsigned short* bp = wsB1 + (size_t)kci * 8192 + l * 8;
        short8 b[16];
#pragma unroll
        for (int nt = 0; nt < 8; ++nt) {
            b[2 * nt]     = *(const short8*)(bp + (2 * nt) * 512);
            b[2 * nt + 1] = *(const short8*)(bp + (2 * nt + 1) * 512);
        }

        short8 ahi[2], alo[2];
#pragma unroll
        for (int m = 0; m < 2; ++m) {
            float fa[8];
#pragma unroll
            for (int j = 0; j < 4; ++j) { fa[j] = a0[2 * m][j]; fa[j + 4] = a0[2 * m + 1][j]; }
            split8(fa, ahi[m], alo[m]);
        }
#pragma unroll
        for (int m = 0; m < 2; ++m)
#pragma unroll
            for (int nt = 0; nt < 8; ++nt) {
                acc[m][nt] = __builtin_amdgcn_mfma_f32_16x16x32_bf16(ahi[m], b[2 * nt],     acc[m][nt], 0, 0, 0);
                acc[m][nt] = __builtin_amdgcn_mfma_f32_16x16x32_bf16(ahi[m], b[2 * nt + 1], acc[m][nt], 0, 0, 0);
                acc[m][nt] = __builtin_amdgcn_mfma_f32_16x16x32_bf16(alo[m], b[2 * nt],     acc[m][nt], 0, 0, 0);
            }
#pragma unroll
        for (int i = 0; i < 4; ++i) a0[i] = a1[i];
    }

    // ---- epilogue: tail features + bias + silu -> hs[row][c] ----
    {
        const float sf = step_frac[0];
        float hnv[8], cfv[8];
#pragma unroll
        for (int m = 0; m < 2; ++m)
#pragma unroll
            for (int r = 0; r < 4; ++r) {
                const int row = row0 + m * 16 + quad * 4 + r;
                hnv[m * 4 + r] = hn[row];
                cfv[m * 4 + r] = cf[row];
            }
#pragma unroll
        for (int nt = 0; nt < 8; ++nt) {
            const int c = nt * 16 + l15;
            const float w96 = W1[(size_t)4096 * HGL + c];
            const float w97 = W1[(size_t)4097 * HGL + c];
            const float w98 = W1[(size_t)4098 * HGL + c];
            const float bb  = b1[c];
#pragma unroll
            for (int m = 0; m < 2; ++m)
#pragma unroll
                for (int r = 0; r < 4; ++r) {
                    const float x = acc[m][nt][r] + sf * w96 + hnv[m * 4 + r] * w97
                                  + cfv[m * 4 + r] * w98 + bb;
                    hs[(m * 16 + quad * 4 + r) * 132 + c] = x / (1.0f + expf(-x));
                }
        }
    }
    __syncthreads();

    // ---- GEMM2 via MFMA (K=128, E=64), h split on read from LDS ----
    f32x4 acc2[2][4];
#pragma unroll
    for (int m = 0; m < 2; ++m)
#pragma unroll
        for (int nt = 0; nt < 4; ++nt) acc2[m][nt] = (f32x4){0.f, 0.f, 0.f, 0.f};

#pragma unroll
    for (int kc2 = 0; kc2 < 4; ++kc2) {
        const unsigned short* bp2 = wsB2 + kc2 * 4096 + l * 8;
        short8 c2[8];
#pragma unroll
        for (int nt = 0; nt < 4; ++nt) {
            c2[2 * nt]     = *(const short8*)(bp2 + (2 * nt) * 512);
            c2[2 * nt + 1] = *(const short8*)(bp2 + (2 * nt + 1) * 512);
        }
#pragma unroll
        for (int m = 0; m < 2; ++m) {
            const float4 va = *(const float4*)&hs[(m * 16 + l15) * 132 + kc2 * 32 + quad * 8];
            const float4 vb = *(const float4*)&hs[(m * 16 + l15) * 132 + kc2 * 32 + quad * 8 + 4];
            float fa[8];
#pragma unroll
            for (int j = 0; j < 4; ++j) { fa[j] = ((const float*)&va)[j]; fa[j + 4] = ((const float*)&vb)[j]; }
            short8 h2, lo2v;
            split8(fa, h2, lo2v);
#pragma unroll
            for (int nt = 0; nt < 4; ++nt) {
                acc2[m][nt] = __builtin_amdgcn_mfma_f32_16x16x32_bf16(h2,   c2[2 * nt],     acc2[m][nt], 0, 0, 0);
                acc2[m][nt] = __builtin_amdgcn_mfma_f32_16x16x32_bf16(h2,   c2[2 * nt + 1], acc2[m][nt], 0, 0, 0);
                acc2[m][nt] = __builtin_amdgcn_mfma_f32_16x16x32_bf16(lo2v, c2[2 * nt],     acc2[m][nt], 0, 0, 0);
            }
        }
    }

    // ---- logits out + ls stage, zero wt ----
#pragma unroll
    for (int m = 0; m < 2; ++m)
#pragma unroll
        for (int nt = 0; nt < 4; ++nt) {
            const int c = nt * 16 + l15;
            const float bv = b2v[c];
#pragma unroll
            for (int r = 0; r < 4; ++r) {
                const int lr = m * 16 + quad * 4 + r;
                const float v = acc2[m][nt][r] + bv;
                out_l[(size_t)(row0 + lr) * EGL + c] = v;
                ls[lr * 65 + c] = v;
            }
        }
    for (int i = l; i < 32 * 65; i += 64) wt[i] = 0.0f;
    __syncthreads();

    // ---- top-8 (+9th for gap), softmax, scatter, flag near-ties into global list ----
    if (l < 32) {
        float vals[9]; int idxs[9];
#pragma unroll
        for (int i = 0; i < 9; ++i) { vals[i] = -INFINITY; idxs[i] = 0; }
        for (int e = 0; e < EGL; ++e) {
            const float v = ls[l * 65 + e];
            if (v > vals[8]) {
                int p = 8;
                while (p > 0 && v > vals[p - 1]) { vals[p] = vals[p - 1]; idxs[p] = idxs[p - 1]; --p; }
                vals[p] = v; idxs[p] = e;
            }
        }
        const float mx = vals[0];
        float wgt[8], ssum = 0.0f;
#pragma unroll
        for (int i = 0; i < 8; ++i) { wgt[i] = expf(vals[i] - mx); ssum += wgt[i]; }
        const float inv = 1.0f / ssum;
#pragma unroll
        for (int i = 0; i < 8; ++i) wt[l * 65 + idxs[i]] = wgt[i] * inv;
        if (vals[7] - vals[8] < DELTA) {
            int p = atomicAdd(gcount, 1);
            if (p < 16384) glist[p] = row0 + l;
        }
    }
    __syncthreads();

    for (int i = l; i < 32 * EGL; i += 64) {
        const int m = i >> 6, c = i & 63;
        out_w[(size_t)(row0 + m) * EGL + c] = wt[m * 65 + c];
    }
}

// ---- refine: fp32 recompute of listed rows, 1 row per block-iteration ----
__global__ __launch_bounds__(512, 1) void refine_rows(
    const float* __restrict__ r_pooled, const float* __restrict__ step_frac,
    const float* __restrict__ hn, const float* __restrict__ cf,
    const float* __restrict__ W1, const float* __restrict__ b1,
    const float* __restrict__ W2, const float* __restrict__ b2,
    const int* __restrict__ gcount, const int* __restrict__ glist,
    float* __restrict__ out_w)
{
    __shared__ __align__(16) float als[DGL];
    __shared__ float part[4][128];
    __shared__ float hred[128];
    __shared__ float lb[64];
    __shared__ float wb[64];

    const int t = threadIdx.x;
    const int cnt = *gcount;
    const int c = t & 127, sl = t >> 7;

    for (int i = blockIdx.x; i < cnt; i += gridDim.x) {
        const int row = glist[i];
        __syncthreads();
        for (int j = t; j < DGL / 4; j += 512)
            *(float4*)&als[j * 4] = *(const float4*)&r_pooled[(size_t)row * DGL + j * 4];
        __syncthreads();

        float pr = 0.0f;
        const float* ap = als + sl * 1024;
        const float* wp = W1 + (size_t)(sl * 1024) * HGL + c;
#pragma unroll 8
        for (int k = 0; k < 1024; ++k) pr = fmaf(ap[k], wp[(size_t)k * HGL], pr);
        part[sl][c] = pr;
        __syncthreads();

        if (t < 128) {
            const float sf = step_frac[0];
            float x = part[0][t] + part[1][t] + part[2][t] + part[3][t];
            x += sf * W1[(size_t)4096 * HGL + t] + hn[row] * W1[(size_t)4097 * HGL + t]
               + cf[row] * W1[(size_t)4098 * HGL + t] + b1[t];
            hred[t] = x / (1.0f + expf(-x));
        }
        __syncthreads();
        if (t < 64) {
            float a = b2[t];
            for (int k = 0; k < HGL; ++k) a = fmaf(hred[k], W2[k * EGL + t], a);
            lb[t] = a; wb[t] = 0.0f;
        }
        __syncthreads();
        if (t == 0) {
            float vals[8]; int idxs[8];
#pragma unroll
            for (int q = 0; q < 8; ++q) { vals[q] = -INFINITY; idxs[q] = 0; }
            for (int e = 0; e < EGL; ++e) {
                const float v = lb[e];
                if (v > vals[7]) {
                    int p = 7;
                    while (p > 0 && v > vals[p - 1]) { vals[p] = vals[p - 1]; idxs[p] = idxs[p - 1]; --p; }
                    vals[p] = v; idxs[p] = e;
                }
            }
            const float mx = vals[0];
            float wgt[8], ssum = 0.0f;
#pragma unroll
            for (int q = 0; q < 8; ++q) { wgt[q] = expf(vals[q] - mx); ssum += wgt[q]; }
            const float inv = 1.0f / ssum;
#pragma unroll
            for (int q = 0; q < 8; ++q) wb[idxs[q]] = wgt[q] * inv;
        }
        __syncthreads();
        if (t < 64) out_w[(size_t)row * EGL + t] = wb[t];
    }
}

extern "C" void kernel_launch(void* const* d_in, const int* in_sizes, int n_in,
                              void* d_out, int out_size, void* d_ws, size_t ws_size,
                              hipStream_t stream) {
    const float* r_pooled    = (const float*)d_in[0];
    const float* step_frac   = (const float*)d_in[1];
    const float* hidden_norm = (const float*)d_in[2];
    const float* confidence  = (const float*)d_in[3];
    const float* W1          = (const float*)d_in[4];
    const float* b1          = (const float*)d_in[5];
    const float* W2          = (const float*)d_in[6];
    const float* b2          = (const float*)d_in[7];

    const int B = in_sizes[2];
    float* out_w = (float*)d_out;
    float* out_l = out_w + (size_t)B * EGL;

    unsigned short* wsB1 = (unsigned short*)d_ws;                    // 2 MB
    unsigned short* wsB2 = (unsigned short*)((char*)d_ws + 2097152); // 32 KB
    int* gcount = (int*)((char*)d_ws + 2129920);
    int* glist  = (int*)((char*)d_ws + 2129984);                     // 64 KB

    hipLaunchKernelGGL(pack_w1, dim3(1024), dim3(64), 0, stream, W1, wsB1);
    hipLaunchKernelGGL(pack_w2, dim3(16), dim3(64), 0, stream, W2, wsB2, gcount);
    hipLaunchKernelGGL(router_main, dim3(B / 32), dim3(64), 0, stream,
                       r_pooled, step_frac, hidden_norm, confidence,
                       W1, b1, b2, wsB1, wsB2, gcount, glist, out_w, out_l);
    hipLaunchKernelGGL(refine_rows, dim3(256), dim3(512), 0, stream,
                       r_pooled, step_frac, hidden_norm, confidence,
                       W1, b1, W2, b2, gcount, glist, out_w);
}

// Round 4
// 562.145 us; speedup vs baseline: 1.7993x; 1.1025x over previous
//
#include <hip/hip_runtime.h>
#include <math.h>

// B=16384, D=4096 (+3 tail features), H=128, E=64, K=8
#define DGL 4096
#define HGL 128
#define EGL 64
#define DELTA 5e-4f    // top8/9 gap threshold for fp32 recompute (split err sigma ~1.5e-5)

typedef short  short8 __attribute__((ext_vector_type(8)));
typedef float  f32x4  __attribute__((ext_vector_type(4)));

__device__ inline unsigned short bf16_rne(float x) {
    unsigned u = __float_as_uint(x);
    u += 0x7FFFu + ((u >> 16) & 1u);
    return (unsigned short)(u >> 16);
}
// truncation-hi + RNE-lo split: hi+lo represents x to ~2^-17 rel
__device__ inline void split2(float x, short& hi, short& lo) {
    unsigned u = __float_as_uint(x);
    hi = (short)(u >> 16);
    float hif = __uint_as_float(u & 0xFFFF0000u);
    lo = (short)bf16_rne(x - hif);
}
__device__ inline void split8(const float* f, short8& hi, short8& lo) {
#pragma unroll
    for (int j = 0; j < 8; ++j) { short h, l2; split2(f[j], h, l2); hi[j] = h; lo[j] = l2; }
}

// ---- pack W1[0:4096] into bf16 hi/lo MFMA B-fragments (layout verified round 2/3) ----
// wsB1[kci*8192 + ((nt*2+h)*64 + lane)*8 + j]; lane l holds B[k=kci*32+(l>>4)*8+j][n=nt*16+(l&15)]
__global__ void pack_w1(const float* __restrict__ W1, unsigned short* __restrict__ wsB1) {
    const int b = blockIdx.x;              // 1024 = 128 kci * 8 nt
    const int kci = b >> 3, nt = b & 7;
    const int l = threadIdx.x, quad = l >> 4, l15 = l & 15;
    short8 vh, vl;
#pragma unroll
    for (int j = 0; j < 8; ++j) {
        const int k = kci * 32 + quad * 8 + j;
        short h, lo; split2(W1[(size_t)k * HGL + nt * 16 + l15], h, lo);
        vh[j] = h; vl[j] = lo;
    }
    *(short8*)(wsB1 + (size_t)kci * 8192 + ((nt * 2 + 0) * 64 + l) * 8) = vh;
    *(short8*)(wsB1 + (size_t)kci * 8192 + ((nt * 2 + 1) * 64 + l) * 8) = vl;
}

// ---- pack W2 (128x64) frags; also zero the refine-list counter ----
__global__ void pack_w2(const float* __restrict__ W2, unsigned short* __restrict__ wsB2,
                        int* __restrict__ gcount) {
    if (blockIdx.x == 0 && threadIdx.x == 0) *gcount = 0;
    const int b = blockIdx.x;              // 16 = 4 kc2 * 4 nt
    const int kc2 = b >> 2, nt = b & 3;
    const int l = threadIdx.x, quad = l >> 4, l15 = l & 15;
    short8 vh, vl;
#pragma unroll
    for (int j = 0; j < 8; ++j) {
        const int k = kc2 * 32 + quad * 8 + j;
        short h, lo; split2(W2[k * EGL + nt * 16 + l15], h, lo);
        vh[j] = h; vl[j] = lo;
    }
    *(short8*)(wsB2 + ((kc2 * 4 + nt) * 2 + 0) * 512 + l * 8) = vh;
    *(short8*)(wsB2 + ((kc2 * 4 + nt) * 2 + 1) * 512 + l * 8) = vl;
}

// ---- main: 256 threads = 4 waves, 32 rows/block, K split 4-way across waves ----
// No barriers in the K-loop; LDS reduction + epilogue at the end only.
__global__ __launch_bounds__(256, 2) void router_main(
    const float* __restrict__ r_pooled, const float* __restrict__ step_frac,
    const float* __restrict__ hn, const float* __restrict__ cf,
    const float* __restrict__ W1, const float* __restrict__ b1,
    const float* __restrict__ b2v,
    const unsigned short* __restrict__ wsB1, const unsigned short* __restrict__ wsB2,
    int* __restrict__ gcount, int* __restrict__ glist,
    float* __restrict__ out_w, float* __restrict__ out_l)
{
    __shared__ float hsum[32 * 132];  // reduced h, [row][col] stride 132
    __shared__ float ls[32 * 65];     // logits tile for topk
    __shared__ float wt[32 * 65];     // weights tile

    const int t = threadIdx.x;
    const int w = t >> 6, l = t & 63;
    const int quad = l >> 4, l15 = l & 15;
    const int row0 = blockIdx.x * 32;

    // this wave's K-range: kci_glob in [w*32, w*32+32)
    const float* aB0 = r_pooled + (size_t)(row0 + l15) * DGL + w * 1024 + quad * 8;
    const float* aB1 = aB0 + (size_t)16 * DGL;

    f32x4 acc[2][8];
#pragma unroll
    for (int m = 0; m < 2; ++m)
#pragma unroll
        for (int nt = 0; nt < 8; ++nt) acc[m][nt] = (f32x4){0.f, 0.f, 0.f, 0.f};

    float4 a0[4];
    a0[0] = *(const float4*)(aB0);
    a0[1] = *(const float4*)(aB0 + 4);
    a0[2] = *(const float4*)(aB1);
    a0[3] = *(const float4*)(aB1 + 4);

    for (int kci = 0; kci < 32; ++kci) {
        const int kn = (kci + 1 < 32) ? (kci + 1) : 31;
        float4 a1[4];
        a1[0] = *(const float4*)(aB0 + kn * 32);
        a1[1] = *(const float4*)(aB0 + kn * 32 + 4);
        a1[2] = *(const float4*)(aB1 + kn * 32);
        a1[3] = *(const float4*)(aB1 + kn * 32 + 4);

        const unsigned short* bp = wsB1 + (size_t)(w * 32 + kci) * 8192 + l * 8;
        short8 b[16];
#pragma unroll
        for (int nt = 0; nt < 8; ++nt) {
            b[2 * nt]     = *(const short8*)(bp + (2 * nt) * 512);
            b[2 * nt + 1] = *(const short8*)(bp + (2 * nt + 1) * 512);
        }

        short8 ahi[2], alo[2];
#pragma unroll
        for (int m = 0; m < 2; ++m) {
            float fa[8];
#pragma unroll
            for (int j = 0; j < 4; ++j) { fa[j] = a0[2 * m][j]; fa[j + 4] = a0[2 * m + 1][j]; }
            split8(fa, ahi[m], alo[m]);
        }
#pragma unroll
        for (int m = 0; m < 2; ++m)
#pragma unroll
            for (int nt = 0; nt < 8; ++nt) {
                acc[m][nt] = __builtin_amdgcn_mfma_f32_16x16x32_bf16(ahi[m], b[2 * nt],     acc[m][nt], 0, 0, 0);
                acc[m][nt] = __builtin_amdgcn_mfma_f32_16x16x32_bf16(ahi[m], b[2 * nt + 1], acc[m][nt], 0, 0, 0);
                acc[m][nt] = __builtin_amdgcn_mfma_f32_16x16x32_bf16(alo[m], b[2 * nt],     acc[m][nt], 0, 0, 0);
            }
#pragma unroll
        for (int i = 0; i < 4; ++i) a0[i] = a1[i];
    }

    // ---- reduce the 4 K-partials through LDS (sequential wave adds) ----
    // C layout: row_local = m*16 + quad*4 + r, col = nt*16 + l15
    if (w == 0) {
#pragma unroll
        for (int m = 0; m < 2; ++m)
#pragma unroll
            for (int nt = 0; nt < 8; ++nt)
#pragma unroll
                for (int r = 0; r < 4; ++r)
                    hsum[(m * 16 + quad * 4 + r) * 132 + nt * 16 + l15] = acc[m][nt][r];
    }
    __syncthreads();
#pragma unroll
    for (int wv = 1; wv < 4; ++wv) {
        if (w == wv) {
#pragma unroll
            for (int m = 0; m < 2; ++m)
#pragma unroll
                for (int nt = 0; nt < 8; ++nt)
#pragma unroll
                    for (int r = 0; r < 4; ++r)
                        hsum[(m * 16 + quad * 4 + r) * 132 + nt * 16 + l15] += acc[m][nt][r];
        }
        __syncthreads();
    }

    // ---- epilogue: tail features + bias + silu, in place on hsum ----
    {
        const float sf = step_frac[0];
#pragma unroll
        for (int j = 0; j < 16; ++j) {
            const int idx = j * 256 + t;      // 0..4095
            const int r = idx >> 7, c = idx & 127;
            float x = hsum[r * 132 + c];
            x += sf * W1[(size_t)4096 * HGL + c]
               + hn[row0 + r] * W1[(size_t)4097 * HGL + c]
               + cf[row0 + r] * W1[(size_t)4098 * HGL + c] + b1[c];
            hsum[r * 132 + c] = x / (1.0f + expf(-x));
        }
    }
    __syncthreads();

    // ---- GEMM2 via MFMA: each wave does one 16-row x 32-col quadrant ----
    const int mt2 = w >> 1, nh2 = w & 1;
    f32x4 acc2[2];
    acc2[0] = (f32x4){0.f, 0.f, 0.f, 0.f};
    acc2[1] = (f32x4){0.f, 0.f, 0.f, 0.f};
#pragma unroll
    for (int kc2 = 0; kc2 < 4; ++kc2) {
        const float4 va = *(const float4*)&hsum[(mt2 * 16 + l15) * 132 + kc2 * 32 + quad * 8];
        const float4 vb = *(const float4*)&hsum[(mt2 * 16 + l15) * 132 + kc2 * 32 + quad * 8 + 4];
        float fa[8];
#pragma unroll
        for (int j = 0; j < 4; ++j) { fa[j] = ((const float*)&va)[j]; fa[j + 4] = ((const float*)&vb)[j]; }
        short8 h2, lo2;
        split8(fa, h2, lo2);
#pragma unroll
        for (int ntp = 0; ntp < 2; ++ntp) {
            const int nt = nh2 * 2 + ntp;
            const short8 bh = *(const short8*)(wsB2 + ((kc2 * 4 + nt) * 2 + 0) * 512 + l * 8);
            const short8 bl = *(const short8*)(wsB2 + ((kc2 * 4 + nt) * 2 + 1) * 512 + l * 8);
            acc2[ntp] = __builtin_amdgcn_mfma_f32_16x16x32_bf16(h2,  bh, acc2[ntp], 0, 0, 0);
            acc2[ntp] = __builtin_amdgcn_mfma_f32_16x16x32_bf16(h2,  bl, acc2[ntp], 0, 0, 0);
            acc2[ntp] = __builtin_amdgcn_mfma_f32_16x16x32_bf16(lo2, bh, acc2[ntp], 0, 0, 0);
        }
    }

    // ---- logits out + ls stage, zero wt ----
#pragma unroll
    for (int ntp = 0; ntp < 2; ++ntp) {
        const int c = (nh2 * 2 + ntp) * 16 + l15;
        const float bv = b2v[c];
#pragma unroll
        for (int r = 0; r < 4; ++r) {
            const int lr = mt2 * 16 + quad * 4 + r;
            const float v = acc2[ntp][r] + bv;
            out_l[(size_t)(row0 + lr) * EGL + c] = v;
            ls[lr * 65 + c] = v;
        }
    }
    for (int i = t; i < 32 * 65; i += 256) wt[i] = 0.0f;
    __syncthreads();

    // ---- top-8 (+9th for gap), softmax, scatter, flag near-ties ----
    if (t < 32) {
        float vals[9]; int idxs[9];
#pragma unroll
        for (int i = 0; i < 9; ++i) { vals[i] = -INFINITY; idxs[i] = 0; }
        for (int e = 0; e < EGL; ++e) {
            const float v = ls[t * 65 + e];
            if (v > vals[8]) {
                int p = 8;
                while (p > 0 && v > vals[p - 1]) { vals[p] = vals[p - 1]; idxs[p] = idxs[p - 1]; --p; }
                vals[p] = v; idxs[p] = e;
            }
        }
        const float mx = vals[0];
        float wgt[8], ssum = 0.0f;
#pragma unroll
        for (int i = 0; i < 8; ++i) { wgt[i] = expf(vals[i] - mx); ssum += wgt[i]; }
        const float inv = 1.0f / ssum;
#pragma unroll
        for (int i = 0; i < 8; ++i) wt[t * 65 + idxs[i]] = wgt[i] * inv;
        if (vals[7] - vals[8] < DELTA) {
            int p = atomicAdd(gcount, 1);
            if (p < 16384) glist[p] = row0 + t;
        }
    }
    __syncthreads();

    for (int i = t; i < 32 * EGL; i += 256) {
        const int m = i >> 6, c = i & 63;
        out_w[(size_t)(row0 + m) * EGL + c] = wt[m * 65 + c];
    }
}

// ---- refine: fp32 recompute of listed rows ----
__global__ __launch_bounds__(512, 1) void refine_rows(
    const float* __restrict__ r_pooled, const float* __restrict__ step_frac,
    const float* __restrict__ hn, const float* __restrict__ cf,
    const float* __restrict__ W1, const float* __restrict__ b1,
    const float* __restrict__ W2, const float* __restrict__ b2,
    const int* __restrict__ gcount, const int* __restrict__ glist,
    float* __restrict__ out_w)
{
    __shared__ __align__(16) float als[DGL];
    __shared__ float part[4][128];
    __shared__ float hred[128];
    __shared__ float lb[64];
    __shared__ float wb[64];

    const int t = threadIdx.x;
    const int cnt = *gcount;
    const int c = t & 127, sl = t >> 7;

    for (int i = blockIdx.x; i < cnt; i += gridDim.x) {
        const int row = glist[i];
        __syncthreads();
        for (int j = t; j < DGL / 4; j += 512)
            *(float4*)&als[j * 4] = *(const float4*)&r_pooled[(size_t)row * DGL + j * 4];
        __syncthreads();

        float pr = 0.0f;
        const float* ap = als + sl * 1024;
        const float* wp = W1 + (size_t)(sl * 1024) * HGL + c;
#pragma unroll 8
        for (int k = 0; k < 1024; ++k) pr = fmaf(ap[k], wp[(size_t)k * HGL], pr);
        part[sl][c] = pr;
        __syncthreads();

        if (t < 128) {
            const float sf = step_frac[0];
            float x = part[0][t] + part[1][t] + part[2][t] + part[3][t];
            x += sf * W1[(size_t)4096 * HGL + t] + hn[row] * W1[(size_t)4097 * HGL + t]
               + cf[row] * W1[(size_t)4098 * HGL + t] + b1[t];
            hred[t] = x / (1.0f + expf(-x));
        }
        __syncthreads();
        if (t < 64) {
            float a = b2[t];
            for (int k = 0; k < HGL; ++k) a = fmaf(hred[k], W2[k * EGL + t], a);
            lb[t] = a; wb[t] = 0.0f;
        }
        __syncthreads();
        if (t == 0) {
            float vals[8]; int idxs[8];
#pragma unroll
            for (int q = 0; q < 8; ++q) { vals[q] = -INFINITY; idxs[q] = 0; }
            for (int e = 0; e < EGL; ++e) {
                const float v = lb[e];
                if (v > vals[7]) {
                    int p = 7;
                    while (p > 0 && v > vals[p - 1]) { vals[p] = vals[p - 1]; idxs[p] = idxs[p - 1]; --p; }
                    vals[p] = v; idxs[p] = e;
                }
            }
            const float mx = vals[0];
            float wgt[8], ssum = 0.0f;
#pragma unroll
            for (int q = 0; q < 8; ++q) { wgt[q] = expf(vals[q] - mx); ssum += wgt[q]; }
            const float inv = 1.0f / ssum;
#pragma unroll
            for (int q = 0; q < 8; ++q) wb[idxs[q]] = wgt[q] * inv;
        }
        __syncthreads();
        if (t < 64) out_w[(size_t)row * EGL + t] = wb[t];
    }
}

extern "C" void kernel_launch(void* const* d_in, const int* in_sizes, int n_in,
                              void* d_out, int out_size, void* d_ws, size_t ws_size,
                              hipStream_t stream) {
    const float* r_pooled    = (const float*)d_in[0];
    const float* step_frac   = (const float*)d_in[1];
    const float* hidden_norm = (const float*)d_in[2];
    const float* confidence  = (const float*)d_in[3];
    const float* W1          = (const float*)d_in[4];
    const float* b1          = (const float*)d_in[5];
    const float* W2          = (const float*)d_in[6];
    const float* b2          = (const float*)d_in[7];

    const int B = in_sizes[2];
    float* out_w = (float*)d_out;
    float* out_l = out_w + (size_t)B * EGL;

    unsigned short* wsB1 = (unsigned short*)d_ws;                    // 2 MB
    unsigned short* wsB2 = (unsigned short*)((char*)d_ws + 2097152); // 32 KB
    int* gcount = (int*)((char*)d_ws + 2129920);
    int* glist  = (int*)((char*)d_ws + 2129984);                     // 64 KB

    hipLaunchKernelGGL(pack_w1, dim3(1024), dim3(64), 0, stream, W1, wsB1);
    hipLaunchKernelGGL(pack_w2, dim3(16), dim3(64), 0, stream, W2, wsB2, gcount);
    hipLaunchKernelGGL(router_main, dim3(B / 32), dim3(256), 0, stream,
                       r_pooled, step_frac, hidden_norm, confidence,
                       W1, b1, b2, wsB1, wsB2, gcount, glist, out_w, out_l);
    hipLaunchKernelGGL(refine_rows, dim3(256), dim3(512), 0, stream,
                       r_pooled, step_frac, hidden_norm, confidence,
                       W1, b1, W2, b2, gcount, glist, out_w);
}